// Round 1
// baseline (692.150 us; speedup 1.0000x reference)
//
#include <hip/hip_runtime.h>

typedef unsigned short u16;
typedef unsigned int u32;

using short8 = __attribute__((ext_vector_type(8))) short;
using f32x4  = __attribute__((ext_vector_type(4))) float;
using float4v = __attribute__((ext_vector_type(4))) float;

#define LOG2E 1.44269504088896340736f

// X1 row (per batch): [h1 0:128 | pad] (u16)
#define X1S 136
// H2 row: [h2 0:64 | pad]
#define H2S 72
#define DBS 40
// XCH row stride: 8 steps * 40 + 8 pad (656 B: 16B-aligned, bank-stride 4)
#define XCS 328

__device__ __forceinline__ u16 f2bf(float f) {
  u32 u = __float_as_uint(f);
  return (u16)((u + 0x7FFFu + ((u >> 16) & 1u)) >> 16);
}
__device__ __forceinline__ float sigm(float x) {
  return __builtin_amdgcn_rcpf(1.0f + __builtin_amdgcn_exp2f(-LOG2E * x));
}
__device__ __forceinline__ float tanh_(float x) {
  return 1.0f - 2.0f * __builtin_amdgcn_rcpf(1.0f + __builtin_amdgcn_exp2f(2.0f * LOG2E * x));
}
__device__ __forceinline__ f32x4 mfma_(short8 a, short8 b, f32x4 c) {
  return __builtin_amdgcn_mfma_f32_16x16x32_bf16(a, b, c, 0, 0, 0);
}

// R14 = R13 + wave specialization (768 threads, 12 waves, 3/SIMD):
//  - waves 0-7: L1 only; waves 8-11: L2 + chunk loader; wave 8: decoder head
//  - per-SIMD: {2x L1, 1x L2} concurrent streams (was: A-wave serialized L2+L1)
//  - decoder head single-wave (both Wd tiles + Wf), intra-wave LDS ordering
//    -> 3 barriers/decoder step instead of 4; L1 h-path overlapped with L2+head wait
//  - encoder chunk loads split issue-early/write-late (hide HBM under L2 MFMAs)
__global__ __launch_bounds__(768) void spc_lstm(
    const float* __restrict__ xh,   const float* __restrict__ xfr,
    const float* __restrict__ Wih1, const float* __restrict__ Whh1,
    const float* __restrict__ bih1, const float* __restrict__ bhh1,
    const float* __restrict__ Wih2, const float* __restrict__ Whh2,
    const float* __restrict__ bih2, const float* __restrict__ bhh2,
    const float* __restrict__ Wd,   const float* __restrict__ bd,
    const float* __restrict__ Wf,   const float* __restrict__ bfv,
    const float* __restrict__ ob,   float* __restrict__ out)
{
  __shared__ __align__(16) u16 X1[2][16 * X1S];   //  8704 B
  __shared__ __align__(16) u16 H2B[2][16 * H2S];  //  4608 B
  __shared__ __align__(16) u16 DB[16 * DBS];      //  1280 B
  __shared__ __align__(16) u16 W1xF[32 * 512];    // 32768 B (zeros k>=16 baked)
  __shared__ __align__(16) u16 W2F[64 * 512];     // 65536 B
  __shared__ __align__(16) u16 WdF[4 * 512];      //  4096 B
  __shared__ __align__(16) u16 WfF[512];          //  1024 B
  __shared__ __align__(16) u16 XCH[2][16 * XCS];  // 20992 B x chunk ring
  // total ~135.8 KB

  const int tid = threadIdx.x;
  const int wv  = tid >> 6;          // 0..11
  const int l   = tid & 63;
  const int c   = l & 15;
  const int q   = l >> 4;
  const int bb  = blockIdx.x << 4;
  const bool isL1 = (wv < 8);        // waves 0-7: L1 tiles
  const bool isL2 = !isL1;           // waves 8-11: L2 + loader + head
  const int  wv8  = wv - 8;          // 0..3 for L2 waves

  short8 w1h[4][4];                  // L1 waves: Whh1 frags (64 VGPR)
  short8 w2h[4][2];                  // L2 waves: Whh2 frags (32 VGPR)
  float  b1r[4] = {0.f, 0.f, 0.f, 0.f};
  float  b2r[4] = {0.f, 0.f, 0.f, 0.f};

  // ---- zero activation + chunk LDS ----
  for (int i = tid; i < 2 * 16 * X1S; i += 768) ((u16*)X1)[i] = 0;
  for (int i = tid; i < 2 * 16 * H2S; i += 768) ((u16*)H2B)[i] = 0;
  for (int i = tid; i < 16 * DBS; i += 768) DB[i] = 0;
  for (int i = tid; i < 2 * 16 * XCS; i += 768) ((u16*)XCH)[i] = 0;
  __syncthreads();

  // ---- weight LDS fills (fragment-linear: (k,n) -> ((k>>3)*16+n)*8 + (k&7)) ----
  for (int i = tid; i < 64 * 512; i += 768) {         // Wih2 tiles (ww, ty, kc)
    const int rid = i >> 9, e = i & 511, k = e >> 4, n = e & 15;
    const int ww = rid >> 4, ty = (rid >> 2) & 3, kc = rid & 3;
    const int g = ty * 64 + ww * 16 + n;
    W2F[rid * 512 + ((k >> 3) * 16 + n) * 8 + (k & 7)] = f2bf(Wih2[g * 128 + kc * 32 + k]);
  }
  for (int i = tid; i < 32 * 512; i += 768) {         // Wih1 x-frags FULL (zeros k>=16)
    const int T = i >> 9, e = i & 511, k = e >> 4, n = e & 15;
    const int ty = T >> 3, uv = T & 7;
    const int g = ty * 128 + uv * 16 + n;
    W1xF[T * 512 + ((k >> 3) * 16 + n) * 8 + (k & 7)] =
        (k < 16) ? f2bf(Wih1[g * 16 + k]) : (u16)0;
  }
  for (int i = tid; i < 4 * 512; i += 768) {          // Wd tiles (ww, kc2)
    const int tix = i >> 9, e = i & 511, k = e >> 4, n = e & 15;
    const int ww = tix >> 1, kc2 = tix & 1;
    WdF[tix * 512 + ((k >> 3) * 16 + n) * 8 + (k & 7)] =
        f2bf(Wd[(ww * 16 + n) * 64 + kc2 * 32 + k]);
  }
  {                                                   // Wf (zeros n>=2)
    const int k = tid >> 4, n = tid & 15;
    if (tid < 512)
      WfF[((k >> 3) * 16 + n) * 8 + (k & 7)] = (n < 2) ? f2bf(Wf[n * 32 + k]) : (u16)0;
  }

  // ---- chunk 0 load (L2 waves): steps 0-7 into XCH[0] ----
  if (isL2) {
    const int i0 = tid - 512;
    #pragma unroll
    for (int p = 0; p < 2; p++) {
      const int idx = i0 + p * 256;
      const int r = idx >> 5, rem = idx & 31, st = rem >> 2, hf = rem & 3;
      const float4v v = *(const float4v*)&xh[(bb + r) * 3200 + st * 16 + hf * 4];
      u16* d = &XCH[0][r * XCS + st * 40 + hf * 4];
      d[0] = f2bf(v[0]); d[1] = f2bf(v[1]); d[2] = f2bf(v[2]); d[3] = f2bf(v[3]);
    }
  }

  // ---- register weights / biases ----
  if (isL1) {
    #pragma unroll
    for (int ty = 0; ty < 4; ty++) {
      const int g = ty * 128 + wv * 16 + c;
      b1r[ty] = bih1[g] + bhh1[g];
      #pragma unroll
      for (int kc = 0; kc < 4; kc++) {
        short8 v;
        #pragma unroll
        for (int j = 0; j < 8; j++)
          v[j] = (short)f2bf(Whh1[g * 128 + kc * 32 + q * 8 + j]);
        w1h[ty][kc] = v;
      }
    }
  } else {
    #pragma unroll
    for (int ty = 0; ty < 4; ty++) {
      const int g2 = ty * 64 + wv8 * 16 + c;
      b2r[ty] = bih2[g2] + bhh2[g2];
      #pragma unroll
      for (int kc = 0; kc < 2; kc++) {
        short8 v;
        #pragma unroll
        for (int j = 0; j < 8; j++)
          v[j] = (short)f2bf(Whh2[g2 * 64 + kc * 32 + q * 8 + j]);
        w2h[ty][kc] = v;
      }
    }
  }
  float bdr0 = 0.f, bdr1 = 0.f, bfr = 0.f;
  if (wv == 8) {
    bdr0 = bd[c];
    bdr1 = bd[16 + c];
    if (c < 2) bfr = bfv[c] + ob[c];
  }

  f32x4 c1 = (f32x4){0,0,0,0};
  f32x4 c2 = (f32x4){0,0,0,0};
  __syncthreads();

  for (int t = 0; t <= 220; t++) {
    u16* Xc    = X1[t & 1];        // h1(t-1)
    u16* Xn    = X1[(t + 1) & 1];  // h1(t) dest
    u16* Hprev = H2B[t & 1];       // h2(t-2)
    u16* Hdst  = H2B[(t + 1) & 1]; // h2(t-1) dest
    const bool dec  = (t >= 201);
    const bool doL1 = isL1 && (t <= 219);
    const bool doL2 = isL2 && (t >= 1);

    // ---- loader (L2 waves), 1x per 8 steps; encoder chunks split issue/write ----
    const int  cm    = (t >> 3) + 1;
    const bool ldEnc = isL2 && ((t & 7) == 0) && (cm <= 24);
    float4v stg0, stg1;
    if (ldEnc) {                           // issue loads early, hide under L2 MFMAs
      const int i0 = tid - 512;
      const int t0 = cm << 3;
      {
        const int r = i0 >> 5, rem = i0 & 31, st = rem >> 2, hf = rem & 3;
        stg0 = *(const float4v*)&xh[(bb + r) * 3200 + (t0 + st) * 16 + hf * 4];
      }
      {
        const int idx = i0 + 256;
        const int r = idx >> 5, rem = idx & 31, st = rem >> 2, hf = rem & 3;
        stg1 = *(const float4v*)&xh[(bb + r) * 3200 + (t0 + st) * 16 + hf * 4];
      }
    }

    // ---- L2 for step t-1 (waves 8-11) ----
    if (doL2) {
      f32x4 acc2[4];
      #pragma unroll
      for (int ty = 0; ty < 4; ty++)
        acc2[ty] = (f32x4){b2r[ty], b2r[ty], b2r[ty], b2r[ty]};
      #pragma unroll
      for (int kc = 0; kc < 4; kc++) {
        const short8 fhi = *(const short8*)&Xc[c * X1S + kc * 32 + q * 8];
        #pragma unroll
        for (int ty = 0; ty < 4; ty++) {
          const short8 wf_ = *(const short8*)&W2F[(wv8 * 16 + ty * 4 + kc) * 512 + l * 8];
          acc2[ty] = mfma_(fhi, wf_, acc2[ty]);
        }
      }
      #pragma unroll
      for (int kc = 0; kc < 2; kc++) {
        const short8 hhi = *(const short8*)&Hprev[c * H2S + kc * 32 + q * 8];
        #pragma unroll
        for (int ty = 0; ty < 4; ty++)
          acc2[ty] = mfma_(hhi, w2h[ty][kc], acc2[ty]);
      }
      const int u = wv8 * 16 + c;
      #pragma unroll
      for (int r = 0; r < 4; r++) {
        float ig = sigm(acc2[0][r]);
        float fg = sigm(acc2[1][r]);
        float gg = tanh_(acc2[2][r]);
        float og = sigm(acc2[3][r]);
        float cn = fg * c2[r] + ig * gg;
        float hn = og * tanh_(cn);
        c2[r] = cn;
        Hdst[(q * 4 + r) * H2S + u] = f2bf(hn);
      }
    }

    // ---- loader: write staged encoder chunk / inline decoder chunks ----
    if (ldEnc) {
      u16* dst = XCH[cm & 1];
      const int i0 = tid - 512;
      {
        const int r = i0 >> 5, rem = i0 & 31, st = rem >> 2, hf = rem & 3;
        u16* d = &dst[r * XCS + st * 40 + hf * 4];
        d[0] = f2bf(stg0[0]); d[1] = f2bf(stg0[1]); d[2] = f2bf(stg0[2]); d[3] = f2bf(stg0[3]);
      }
      {
        const int idx = i0 + 256;
        const int r = idx >> 5, rem = idx & 31, st = rem >> 2, hf = rem & 3;
        u16* d = &dst[r * XCS + st * 40 + hf * 4];
        d[0] = f2bf(stg1[0]); d[1] = f2bf(stg1[1]); d[2] = f2bf(stg1[2]); d[3] = f2bf(stg1[3]);
      }
    } else if (isL2 && (t & 7) == 0 && cm <= 27) {    // decoder chunks 25-27
      u16* dst = XCH[cm & 1];
      const int t0 = cm << 3;
      for (int e = tid - 512; e < 16 * 8 * 14; e += 256) {
        const int r = e / 112, rem2 = e % 112, st = rem2 / 14, f = rem2 % 14;
        const int s8 = t0 + st;
        if (s8 < 220)
          dst[r * XCS + st * 40 + f] = f2bf(xfr[(bb + r) * 280 + (s8 - 200) * 14 + f]);
      }
      if (cm == 25) {                  // s=0 feats 14,15 from x_history[..,199,..]
        const int e = tid - 512;
        if (e < 32) {
          const int r = e >> 1, f = 14 + (e & 1);
          dst[r * XCS + f] = f2bf(xh[(bb + r) * 3200 + 199 * 16 + f]);
        }
      }
    }

    // ---- L1(t) h-path (waves 0-7): no pred dependency, overlaps L2/head ----
    f32x4 acc1[4];
    if (doL1) {
      #pragma unroll
      for (int ty = 0; ty < 4; ty++)
        acc1[ty] = (f32x4){b1r[ty], b1r[ty], b1r[ty], b1r[ty]};
      #pragma unroll
      for (int kc = 0; kc < 4; kc++) {
        const short8 ahi = *(const short8*)&Xc[c * X1S + kc * 32 + q * 8];
        #pragma unroll
        for (int ty = 0; ty < 4; ty++)
          acc1[ty] = mfma_(ahi, w1h[ty][kc], acc1[ty]);
      }
    }

    // ---- decoder head: single wave, intra-wave LDS ordering (no mid-barrier) ----
    if (dec) {
      __syncthreads();                 // #1: h2(t-1) visible
      if (wv == 8) {
        f32x4 accd0 = (f32x4){bdr0, bdr0, bdr0, bdr0};
        f32x4 accd1 = (f32x4){bdr1, bdr1, bdr1, bdr1};
        #pragma unroll
        for (int kc = 0; kc < 2; kc++) {
          const short8 ad = *(const short8*)&Hdst[c * H2S + kc * 32 + q * 8];
          accd0 = mfma_(ad, *(const short8*)&WdF[(0 * 2 + kc) * 512 + l * 8], accd0);
          accd1 = mfma_(ad, *(const short8*)&WdF[(1 * 2 + kc) * 512 + l * 8], accd1);
        }
        #pragma unroll
        for (int r = 0; r < 4; r++) {
          DB[(q * 4 + r) * DBS + c]      = f2bf(fmaxf(accd0[r], 0.f));
          DB[(q * 4 + r) * DBS + 16 + c] = f2bf(fmaxf(accd1[r], 0.f));
        }
        // same-wave write->read: compiler inserts lgkmcnt(0)
        const short8 ap  = *(const short8*)&DB[c * DBS + q * 8];
        const short8 wfv = *(const short8*)&WfF[l * 8];
        f32x4 accp = (f32x4){bfr, bfr, bfr, bfr};
        accp = mfma_(ap, wfv, accp);
        if (c < 2) {
          u16* slot = &XCH[(t >> 3) & 1][0];
          #pragma unroll
          for (int r = 0; r < 4; r++) {
            const int b = q * 4 + r;
            out[(bb + b) * 40 + (t - 201) * 2 + c] = accp[r];
            slot[b * XCS + (t & 7) * 40 + 14 + c] = f2bf(accp[r]);  // pred -> x(t)
          }
        }
      }
      __syncthreads();                 // #2: pred in XCH visible
    }

    // ---- L1(t) x-path + epilogue (waves 0-7) ----
    if (doL1) {
      {
        const short8 ax =
            *(const short8*)&XCH[(t >> 3) & 1][c * XCS + (t & 7) * 40 + q * 8];
        #pragma unroll
        for (int ty = 0; ty < 4; ty++) {
          const short8 wxv = *(const short8*)&W1xF[(ty * 8 + wv) * 512 + l * 8];
          acc1[ty] = mfma_(ax, wxv, acc1[ty]);
        }
      }
      const int u = wv * 16 + c;
      #pragma unroll
      for (int r = 0; r < 4; r++) {
        float ig = sigm(acc1[0][r]);
        float fg = sigm(acc1[1][r]);
        float gg = tanh_(acc1[2][r]);
        float og = sigm(acc1[3][r]);
        float cn = fg * c1[r] + ig * gg;
        float hn = og * tanh_(cn);
        c1[r] = cn;
        Xn[(q * 4 + r) * X1S + u] = f2bf(hn);
      }
    }
    __syncthreads();                   // end: h1(t), h2(t-1), chunk data published
  }
}

extern "C" void kernel_launch(void* const* d_in, const int* in_sizes, int n_in,
                              void* d_out, int out_size, void* d_ws, size_t ws_size,
                              hipStream_t stream) {
  (void)in_sizes; (void)n_in; (void)out_size; (void)d_ws; (void)ws_size;
  spc_lstm<<<dim3(256), dim3(768), 0, stream>>>(
      (const float*)d_in[0],  (const float*)d_in[1],
      (const float*)d_in[2],  (const float*)d_in[3],
      (const float*)d_in[4],  (const float*)d_in[5],
      (const float*)d_in[6],  (const float*)d_in[7],
      (const float*)d_in[8],  (const float*)d_in[9],
      (const float*)d_in[10], (const float*)d_in[11],
      (const float*)d_in[12], (const float*)d_in[13],
      (const float*)d_in[14], (float*)d_out);
}

// Round 2
// 495.847 us; speedup vs baseline: 1.3959x; 1.3959x over previous
//
#include <hip/hip_runtime.h>

typedef unsigned short u16;
typedef unsigned int u32;

using short8 = __attribute__((ext_vector_type(8))) short;
using f32x4  = __attribute__((ext_vector_type(4))) float;
using float4v = __attribute__((ext_vector_type(4))) float;

#define LOG2E 1.44269504088896340736f

// X1 row (per batch): [h1 0:128 | pad] (u16)
#define X1S 136
// H2 row: [h2 0:64 | pad]
#define H2S 72
#define DBS 40
// XCH row stride: 8 steps * 40 + 8 pad (656 B: 16B-aligned, bank-stride 4)
#define XCS 328

__device__ __forceinline__ u16 f2bf(float f) {
  u32 u = __float_as_uint(f);
  return (u16)((u + 0x7FFFu + ((u >> 16) & 1u)) >> 16);
}
__device__ __forceinline__ float sigm(float x) {
  return __builtin_amdgcn_rcpf(1.0f + __builtin_amdgcn_exp2f(-LOG2E * x));
}
__device__ __forceinline__ float tanh_(float x) {
  return 1.0f - 2.0f * __builtin_amdgcn_rcpf(1.0f + __builtin_amdgcn_exp2f(2.0f * LOG2E * x));
}
__device__ __forceinline__ f32x4 mfma_(short8 a, short8 b, f32x4 c) {
  return __builtin_amdgcn_mfma_f32_16x16x32_bf16(a, b, c, 0, 0, 0);
}

// R15 = R14 (wave specialization, 768 thr) + spill fix:
//  - __launch_bounds__(768, 3): 3 waves/SIMD -> VGPR cap ~168 (R14 spilled at 84:
//    WRITE_SIZE was 90 MB of scratch traffic)
//  - role-overlaid registers: waves are specialized, so Whh1/Whh2 share wreg[4][4]
//    (L2 waves use [ty][0..1] only), biases share br[4], cell state shares cst
//    -> persistent state 96+16 -> 72 VGPRs, fits without spill
__global__ __launch_bounds__(768, 3) void spc_lstm(
    const float* __restrict__ xh,   const float* __restrict__ xfr,
    const float* __restrict__ Wih1, const float* __restrict__ Whh1,
    const float* __restrict__ bih1, const float* __restrict__ bhh1,
    const float* __restrict__ Wih2, const float* __restrict__ Whh2,
    const float* __restrict__ bih2, const float* __restrict__ bhh2,
    const float* __restrict__ Wd,   const float* __restrict__ bd,
    const float* __restrict__ Wf,   const float* __restrict__ bfv,
    const float* __restrict__ ob,   float* __restrict__ out)
{
  __shared__ __align__(16) u16 X1[2][16 * X1S];   //  8704 B
  __shared__ __align__(16) u16 H2B[2][16 * H2S];  //  4608 B
  __shared__ __align__(16) u16 DB[16 * DBS];      //  1280 B
  __shared__ __align__(16) u16 W1xF[32 * 512];    // 32768 B (zeros k>=16 baked)
  __shared__ __align__(16) u16 W2F[64 * 512];     // 65536 B
  __shared__ __align__(16) u16 WdF[4 * 512];      //  4096 B
  __shared__ __align__(16) u16 WfF[512];          //  1024 B
  __shared__ __align__(16) u16 XCH[2][16 * XCS];  // 20992 B x chunk ring
  // total ~135.8 KB

  const int tid = threadIdx.x;
  const int wv  = tid >> 6;          // 0..11
  const int l   = tid & 63;
  const int c   = l & 15;
  const int q   = l >> 4;
  const int bb  = blockIdx.x << 4;
  const bool isL1 = (wv < 8);        // waves 0-7: L1 tiles
  const bool isL2 = !isL1;           // waves 8-11: L2 + loader + head
  const int  wv8  = wv - 8;          // 0..3 for L2 waves

  // Role-overlaid persistent registers:
  //  L1 waves: wreg[ty][0..3] = Whh1 frags, br = bih1+bhh1, cst = c1
  //  L2 waves: wreg[ty][0..1] = Whh2 frags, br = bih2+bhh2, cst = c2
  short8 wreg[4][4];
  float  br[4];
  f32x4  cst = (f32x4){0,0,0,0};

  // ---- zero activation + chunk LDS ----
  for (int i = tid; i < 2 * 16 * X1S; i += 768) ((u16*)X1)[i] = 0;
  for (int i = tid; i < 2 * 16 * H2S; i += 768) ((u16*)H2B)[i] = 0;
  for (int i = tid; i < 16 * DBS; i += 768) DB[i] = 0;
  for (int i = tid; i < 2 * 16 * XCS; i += 768) ((u16*)XCH)[i] = 0;
  __syncthreads();

  // ---- weight LDS fills (fragment-linear: (k,n) -> ((k>>3)*16+n)*8 + (k&7)) ----
  for (int i = tid; i < 64 * 512; i += 768) {         // Wih2 tiles (ww, ty, kc)
    const int rid = i >> 9, e = i & 511, k = e >> 4, n = e & 15;
    const int ww = rid >> 4, ty = (rid >> 2) & 3, kc = rid & 3;
    const int g = ty * 64 + ww * 16 + n;
    W2F[rid * 512 + ((k >> 3) * 16 + n) * 8 + (k & 7)] = f2bf(Wih2[g * 128 + kc * 32 + k]);
  }
  for (int i = tid; i < 32 * 512; i += 768) {         // Wih1 x-frags FULL (zeros k>=16)
    const int T = i >> 9, e = i & 511, k = e >> 4, n = e & 15;
    const int ty = T >> 3, uv = T & 7;
    const int g = ty * 128 + uv * 16 + n;
    W1xF[T * 512 + ((k >> 3) * 16 + n) * 8 + (k & 7)] =
        (k < 16) ? f2bf(Wih1[g * 16 + k]) : (u16)0;
  }
  for (int i = tid; i < 4 * 512; i += 768) {          // Wd tiles (ww, kc2)
    const int tix = i >> 9, e = i & 511, k = e >> 4, n = e & 15;
    const int ww = tix >> 1, kc2 = tix & 1;
    WdF[tix * 512 + ((k >> 3) * 16 + n) * 8 + (k & 7)] =
        f2bf(Wd[(ww * 16 + n) * 64 + kc2 * 32 + k]);
  }
  {                                                   // Wf (zeros n>=2)
    const int k = tid >> 4, n = tid & 15;
    if (tid < 512)
      WfF[((k >> 3) * 16 + n) * 8 + (k & 7)] = (n < 2) ? f2bf(Wf[n * 32 + k]) : (u16)0;
  }

  // ---- chunk 0 load (L2 waves): steps 0-7 into XCH[0] ----
  if (isL2) {
    const int i0 = tid - 512;
    #pragma unroll
    for (int p = 0; p < 2; p++) {
      const int idx = i0 + p * 256;
      const int r = idx >> 5, rem = idx & 31, st = rem >> 2, hf = rem & 3;
      const float4v v = *(const float4v*)&xh[(bb + r) * 3200 + st * 16 + hf * 4];
      u16* d = &XCH[0][r * XCS + st * 40 + hf * 4];
      d[0] = f2bf(v[0]); d[1] = f2bf(v[1]); d[2] = f2bf(v[2]); d[3] = f2bf(v[3]);
    }
  }

  // ---- register weights / biases (role-overlaid) ----
  if (isL1) {
    #pragma unroll
    for (int ty = 0; ty < 4; ty++) {
      const int g = ty * 128 + wv * 16 + c;
      br[ty] = bih1[g] + bhh1[g];
      #pragma unroll
      for (int kc = 0; kc < 4; kc++) {
        short8 v;
        #pragma unroll
        for (int j = 0; j < 8; j++)
          v[j] = (short)f2bf(Whh1[g * 128 + kc * 32 + q * 8 + j]);
        wreg[ty][kc] = v;
      }
    }
  } else {
    #pragma unroll
    for (int ty = 0; ty < 4; ty++) {
      const int g2 = ty * 64 + wv8 * 16 + c;
      br[ty] = bih2[g2] + bhh2[g2];
      #pragma unroll
      for (int kc = 0; kc < 2; kc++) {
        short8 v;
        #pragma unroll
        for (int j = 0; j < 8; j++)
          v[j] = (short)f2bf(Whh2[g2 * 64 + kc * 32 + q * 8 + j]);
        wreg[ty][kc] = v;
      }
    }
  }
  float bdr0 = 0.f, bdr1 = 0.f, bfr = 0.f;
  if (wv == 8) {
    bdr0 = bd[c];
    bdr1 = bd[16 + c];
    if (c < 2) bfr = bfv[c] + ob[c];
  }

  __syncthreads();

  for (int t = 0; t <= 220; t++) {
    u16* Xc    = X1[t & 1];        // h1(t-1)
    u16* Xn    = X1[(t + 1) & 1];  // h1(t) dest
    u16* Hprev = H2B[t & 1];       // h2(t-2)
    u16* Hdst  = H2B[(t + 1) & 1]; // h2(t-1) dest
    const bool dec  = (t >= 201);
    const bool doL1 = isL1 && (t <= 219);
    const bool doL2 = isL2 && (t >= 1);

    // ---- loader (L2 waves), 1x per 8 steps; encoder chunks split issue/write ----
    const int  cm    = (t >> 3) + 1;
    const bool ldEnc = isL2 && ((t & 7) == 0) && (cm <= 24);
    float4v stg0, stg1;
    if (ldEnc) {                           // issue loads early, hide under L2 MFMAs
      const int i0 = tid - 512;
      const int t0 = cm << 3;
      {
        const int r = i0 >> 5, rem = i0 & 31, st = rem >> 2, hf = rem & 3;
        stg0 = *(const float4v*)&xh[(bb + r) * 3200 + (t0 + st) * 16 + hf * 4];
      }
      {
        const int idx = i0 + 256;
        const int r = idx >> 5, rem = idx & 31, st = rem >> 2, hf = rem & 3;
        stg1 = *(const float4v*)&xh[(bb + r) * 3200 + (t0 + st) * 16 + hf * 4];
      }
    }

    // ---- L2 for step t-1 (waves 8-11) ----
    if (doL2) {
      f32x4 acc2[4];
      #pragma unroll
      for (int ty = 0; ty < 4; ty++)
        acc2[ty] = (f32x4){br[ty], br[ty], br[ty], br[ty]};
      #pragma unroll
      for (int kc = 0; kc < 4; kc++) {
        const short8 fhi = *(const short8*)&Xc[c * X1S + kc * 32 + q * 8];
        #pragma unroll
        for (int ty = 0; ty < 4; ty++) {
          const short8 wf_ = *(const short8*)&W2F[(wv8 * 16 + ty * 4 + kc) * 512 + l * 8];
          acc2[ty] = mfma_(fhi, wf_, acc2[ty]);
        }
      }
      #pragma unroll
      for (int kc = 0; kc < 2; kc++) {
        const short8 hhi = *(const short8*)&Hprev[c * H2S + kc * 32 + q * 8];
        #pragma unroll
        for (int ty = 0; ty < 4; ty++)
          acc2[ty] = mfma_(hhi, wreg[ty][kc], acc2[ty]);
      }
      const int u = wv8 * 16 + c;
      #pragma unroll
      for (int r = 0; r < 4; r++) {
        float ig = sigm(acc2[0][r]);
        float fg = sigm(acc2[1][r]);
        float gg = tanh_(acc2[2][r]);
        float og = sigm(acc2[3][r]);
        float cn = fg * cst[r] + ig * gg;
        float hn = og * tanh_(cn);
        cst[r] = cn;
        Hdst[(q * 4 + r) * H2S + u] = f2bf(hn);
      }
    }

    // ---- loader: write staged encoder chunk / inline decoder chunks ----
    if (ldEnc) {
      u16* dst = XCH[cm & 1];
      const int i0 = tid - 512;
      {
        const int r = i0 >> 5, rem = i0 & 31, st = rem >> 2, hf = rem & 3;
        u16* d = &dst[r * XCS + st * 40 + hf * 4];
        d[0] = f2bf(stg0[0]); d[1] = f2bf(stg0[1]); d[2] = f2bf(stg0[2]); d[3] = f2bf(stg0[3]);
      }
      {
        const int idx = i0 + 256;
        const int r = idx >> 5, rem = idx & 31, st = rem >> 2, hf = rem & 3;
        u16* d = &dst[r * XCS + st * 40 + hf * 4];
        d[0] = f2bf(stg1[0]); d[1] = f2bf(stg1[1]); d[2] = f2bf(stg1[2]); d[3] = f2bf(stg1[3]);
      }
    } else if (isL2 && (t & 7) == 0 && cm <= 27) {    // decoder chunks 25-27
      u16* dst = XCH[cm & 1];
      const int t0 = cm << 3;
      for (int e = tid - 512; e < 16 * 8 * 14; e += 256) {
        const int r = e / 112, rem2 = e % 112, st = rem2 / 14, f = rem2 % 14;
        const int s8 = t0 + st;
        if (s8 < 220)
          dst[r * XCS + st * 40 + f] = f2bf(xfr[(bb + r) * 280 + (s8 - 200) * 14 + f]);
      }
      if (cm == 25) {                  // s=0 feats 14,15 from x_history[..,199,..]
        const int e = tid - 512;
        if (e < 32) {
          const int r = e >> 1, f = 14 + (e & 1);
          dst[r * XCS + f] = f2bf(xh[(bb + r) * 3200 + 199 * 16 + f]);
        }
      }
    }

    // ---- L1(t) h-path (waves 0-7): no pred dependency, overlaps L2/head ----
    f32x4 acc1[4];
    if (doL1) {
      #pragma unroll
      for (int ty = 0; ty < 4; ty++)
        acc1[ty] = (f32x4){br[ty], br[ty], br[ty], br[ty]};
      #pragma unroll
      for (int kc = 0; kc < 4; kc++) {
        const short8 ahi = *(const short8*)&Xc[c * X1S + kc * 32 + q * 8];
        #pragma unroll
        for (int ty = 0; ty < 4; ty++)
          acc1[ty] = mfma_(ahi, wreg[ty][kc], acc1[ty]);
      }
    }

    // ---- decoder head: single wave, intra-wave LDS ordering (no mid-barrier) ----
    if (dec) {
      __syncthreads();                 // #1: h2(t-1) visible
      if (wv == 8) {
        f32x4 accd0 = (f32x4){bdr0, bdr0, bdr0, bdr0};
        f32x4 accd1 = (f32x4){bdr1, bdr1, bdr1, bdr1};
        #pragma unroll
        for (int kc = 0; kc < 2; kc++) {
          const short8 ad = *(const short8*)&Hdst[c * H2S + kc * 32 + q * 8];
          accd0 = mfma_(ad, *(const short8*)&WdF[(0 * 2 + kc) * 512 + l * 8], accd0);
          accd1 = mfma_(ad, *(const short8*)&WdF[(1 * 2 + kc) * 512 + l * 8], accd1);
        }
        #pragma unroll
        for (int r = 0; r < 4; r++) {
          DB[(q * 4 + r) * DBS + c]      = f2bf(fmaxf(accd0[r], 0.f));
          DB[(q * 4 + r) * DBS + 16 + c] = f2bf(fmaxf(accd1[r], 0.f));
        }
        // same-wave write->read: compiler inserts lgkmcnt(0)
        const short8 ap  = *(const short8*)&DB[c * DBS + q * 8];
        const short8 wfv = *(const short8*)&WfF[l * 8];
        f32x4 accp = (f32x4){bfr, bfr, bfr, bfr};
        accp = mfma_(ap, wfv, accp);
        if (c < 2) {
          u16* slot = &XCH[(t >> 3) & 1][0];
          #pragma unroll
          for (int r = 0; r < 4; r++) {
            const int b = q * 4 + r;
            out[(bb + b) * 40 + (t - 201) * 2 + c] = accp[r];
            slot[b * XCS + (t & 7) * 40 + 14 + c] = f2bf(accp[r]);  // pred -> x(t)
          }
        }
      }
      __syncthreads();                 // #2: pred in XCH visible
    }

    // ---- L1(t) x-path + epilogue (waves 0-7) ----
    if (doL1) {
      {
        const short8 ax =
            *(const short8*)&XCH[(t >> 3) & 1][c * XCS + (t & 7) * 40 + q * 8];
        #pragma unroll
        for (int ty = 0; ty < 4; ty++) {
          const short8 wxv = *(const short8*)&W1xF[(ty * 8 + wv) * 512 + l * 8];
          acc1[ty] = mfma_(ax, wxv, acc1[ty]);
        }
      }
      const int u = wv * 16 + c;
      #pragma unroll
      for (int r = 0; r < 4; r++) {
        float ig = sigm(acc1[0][r]);
        float fg = sigm(acc1[1][r]);
        float gg = tanh_(acc1[2][r]);
        float og = sigm(acc1[3][r]);
        float cn = fg * cst[r] + ig * gg;
        float hn = og * tanh_(cn);
        cst[r] = cn;
        Xn[(q * 4 + r) * X1S + u] = f2bf(hn);
      }
    }
    __syncthreads();                   // end: h1(t), h2(t-1), chunk data published
  }
}

extern "C" void kernel_launch(void* const* d_in, const int* in_sizes, int n_in,
                              void* d_out, int out_size, void* d_ws, size_t ws_size,
                              hipStream_t stream) {
  (void)in_sizes; (void)n_in; (void)out_size; (void)d_ws; (void)ws_size;
  spc_lstm<<<dim3(256), dim3(768), 0, stream>>>(
      (const float*)d_in[0],  (const float*)d_in[1],
      (const float*)d_in[2],  (const float*)d_in[3],
      (const float*)d_in[4],  (const float*)d_in[5],
      (const float*)d_in[6],  (const float*)d_in[7],
      (const float*)d_in[8],  (const float*)d_in[9],
      (const float*)d_in[10], (const float*)d_in[11],
      (const float*)d_in[12], (const float*)d_in[13],
      (const float*)d_in[14], (float*)d_out);
}

// Round 4
// 426.829 us; speedup vs baseline: 1.6216x; 1.1617x over previous
//
#include <hip/hip_runtime.h>

typedef unsigned short u16;
typedef unsigned int u32;

using short8  = __attribute__((ext_vector_type(8))) short;
using f32x4   = __attribute__((ext_vector_type(4))) float;
using float4v = __attribute__((ext_vector_type(4))) float;
using uint2v  = __attribute__((ext_vector_type(2))) unsigned int;

#define LOG2E 1.44269504088896340736f

// X1 row (per batch): [h1 0:128 | pad] (u16)
#define X1S 136
// H2 row: [h2 0:64 | pad]
#define H2S 72
#define DBS 40
// XCH row stride: 8 steps * 40 + 8 pad (656 B: 16B-aligned, bank-stride 4)
#define XCS 328

__device__ __forceinline__ u16 f2bf(float f) {
  u32 u = __float_as_uint(f);
  return (u16)((u + 0x7FFFu + ((u >> 16) & 1u)) >> 16);
}
// packed f32x2 -> bf16x2, RNE (same rounding as f2bf), 1 instr
__device__ __forceinline__ u32 pkbf(float a, float b) {
  u32 r;
  asm("v_cvt_pk_bf16_f32 %0, %1, %2" : "=v"(r) : "v"(a), "v"(b));
  return r;
}
__device__ __forceinline__ float sigm(float x) {
  return __builtin_amdgcn_rcpf(1.0f + __builtin_amdgcn_exp2f(-LOG2E * x));
}
__device__ __forceinline__ float tanh_(float x) {
  return 1.0f - 2.0f * __builtin_amdgcn_rcpf(1.0f + __builtin_amdgcn_exp2f(2.0f * LOG2E * x));
}
__device__ __forceinline__ f32x4 mfma_(short8 a, short8 b, f32x4 c) {
  return __builtin_amdgcn_mfma_f32_16x16x32_bf16(a, b, c, 0, 0, 0);
}
__device__ __forceinline__ float cellr(float gi, float gf, float gg, float go, float& cr) {
  const float ig = sigm(gi), fg = sigm(gf), g = tanh_(gg), og = sigm(go);
  const float cn = fg * cr + ig * g;
  cr = cn;
  return og * tanh_(cn);
}

// R16 = R15 (wave-spec, no-spill) + constant-offset hot loop:
//  - encoder restructured as 25 chunks x 8 fully-unrolled steps: t&1 / t&7 /
//    ring parity become compile-time; all DS offsets fold into immediates
//    (R15 recomputed cndmask+add address chains per access per step)
//  - v_cvt_pk_bf16_f32 for hot f32->bf16 stores (1 instr per pair vs ~9 VALU)
//  - chunk loader stores packed 8B (uint2) instead of 4x u16
//  - s_setprio(1) around MFMA clusters (heterogeneous waves -> T5 regime)
//  - decoder (20 steps) stays rolled: cold path
__global__ __launch_bounds__(768, 3) void spc_lstm(
    const float* __restrict__ xh,   const float* __restrict__ xfr,
    const float* __restrict__ Wih1, const float* __restrict__ Whh1,
    const float* __restrict__ bih1, const float* __restrict__ bhh1,
    const float* __restrict__ Wih2, const float* __restrict__ Whh2,
    const float* __restrict__ bih2, const float* __restrict__ bhh2,
    const float* __restrict__ Wd,   const float* __restrict__ bd,
    const float* __restrict__ Wf,   const float* __restrict__ bfv,
    const float* __restrict__ ob,   float* __restrict__ out)
{
  __shared__ __align__(16) u16 X1[2][16 * X1S];   //  8704 B
  __shared__ __align__(16) u16 H2B[2][16 * H2S];  //  4608 B
  __shared__ __align__(16) u16 DB[16 * DBS];      //  1280 B
  __shared__ __align__(16) u16 W1xF[32 * 512];    // 32768 B (zeros k>=16 baked)
  __shared__ __align__(16) u16 W2F[64 * 512];     // 65536 B
  __shared__ __align__(16) u16 WdF[4 * 512];      //  4096 B
  __shared__ __align__(16) u16 WfF[512];          //  1024 B
  __shared__ __align__(16) u16 XCH[2][16 * XCS];  // 20992 B x chunk ring

  const int tid = threadIdx.x;
  const int wv  = tid >> 6;          // 0..11
  const int l   = tid & 63;
  const int c   = l & 15;
  const int q   = l >> 4;
  const int bb  = blockIdx.x << 4;
  const bool isL1 = (wv < 8);
  const bool isL2 = !isL1;
  const int  wv8  = wv - 8;

  // hoisted lane-offsets (u16 indices)
  const int cX1 = c * X1S, cH2 = c * H2S, cXC = c * XCS;
  const int l8 = l * 8, q8 = q * 8, q4 = q * 4;
  const int u2  = wv * 16 + c;       // L1 unit col
  const int u2b = wv8 * 16 + c;      // L2 unit col
  const int w2o = wv8 * 16;          // W2F tile base

  short8 wreg[4][4];                 // L1: Whh1 frags; L2: Whh2 frags in [ty][0..1]
  float  br[4];
  float  cs0 = 0.f, cs1 = 0.f, cs2 = 0.f, cs3 = 0.f;

  // ---- zero activation + chunk LDS ----
  for (int i = tid; i < 2 * 16 * X1S; i += 768) ((u16*)X1)[i] = 0;
  for (int i = tid; i < 2 * 16 * H2S; i += 768) ((u16*)H2B)[i] = 0;
  for (int i = tid; i < 16 * DBS; i += 768) DB[i] = 0;
  for (int i = tid; i < 2 * 16 * XCS; i += 768) ((u16*)XCH)[i] = 0;
  __syncthreads();

  // ---- weight LDS fills (fragment-linear: (k,n) -> ((k>>3)*16+n)*8 + (k&7)) ----
  for (int i = tid; i < 64 * 512; i += 768) {         // Wih2 tiles (ww, ty, kc)
    const int rid = i >> 9, e = i & 511, k = e >> 4, n = e & 15;
    const int ww = rid >> 4, ty = (rid >> 2) & 3, kc = rid & 3;
    const int g = ty * 64 + ww * 16 + n;
    W2F[rid * 512 + ((k >> 3) * 16 + n) * 8 + (k & 7)] = f2bf(Wih2[g * 128 + kc * 32 + k]);
  }
  for (int i = tid; i < 32 * 512; i += 768) {         // Wih1 x-frags FULL (zeros k>=16)
    const int T = i >> 9, e = i & 511, k = e >> 4, n = e & 15;
    const int ty = T >> 3, uv = T & 7;
    const int g = ty * 128 + uv * 16 + n;
    W1xF[T * 512 + ((k >> 3) * 16 + n) * 8 + (k & 7)] =
        (k < 16) ? f2bf(Wih1[g * 16 + k]) : (u16)0;
  }
  for (int i = tid; i < 4 * 512; i += 768) {          // Wd tiles (ww, kc2)
    const int tix = i >> 9, e = i & 511, k = e >> 4, n = e & 15;
    const int ww = tix >> 1, kc2 = tix & 1;
    WdF[tix * 512 + ((k >> 3) * 16 + n) * 8 + (k & 7)] =
        f2bf(Wd[(ww * 16 + n) * 64 + kc2 * 32 + k]);
  }
  {                                                   // Wf (zeros n>=2)
    const int k = tid >> 4, n = tid & 15;
    if (tid < 512)
      WfF[((k >> 3) * 16 + n) * 8 + (k & 7)] = (n < 2) ? f2bf(Wf[n * 32 + k]) : (u16)0;
  }

  // ---- chunk 0 load (L2 waves): steps 0-7 into XCH[0] ----
  if (isL2) {
    const int i0 = tid - 512;
    #pragma unroll
    for (int p = 0; p < 2; p++) {
      const int idx = i0 + p * 256;
      const int r = idx >> 5, rem = idx & 31, st = rem >> 2, hf = rem & 3;
      const float4v v = *(const float4v*)&xh[(bb + r) * 3200 + st * 16 + hf * 4];
      *(uint2v*)&XCH[0][r * XCS + st * 40 + hf * 4] =
          (uint2v){pkbf(v[0], v[1]), pkbf(v[2], v[3])};
    }
  }

  // ---- register weights / biases (role-overlaid) ----
  if (isL1) {
    #pragma unroll
    for (int ty = 0; ty < 4; ty++) {
      const int g = ty * 128 + wv * 16 + c;
      br[ty] = bih1[g] + bhh1[g];
      #pragma unroll
      for (int kc = 0; kc < 4; kc++) {
        short8 v;
        #pragma unroll
        for (int j = 0; j < 8; j++)
          v[j] = (short)f2bf(Whh1[g * 128 + kc * 32 + q * 8 + j]);
        wreg[ty][kc] = v;
      }
    }
  } else {
    #pragma unroll
    for (int ty = 0; ty < 4; ty++) {
      const int g2 = ty * 64 + wv8 * 16 + c;
      br[ty] = bih2[g2] + bhh2[g2];
      #pragma unroll
      for (int kc = 0; kc < 2; kc++) {
        short8 v;
        #pragma unroll
        for (int j = 0; j < 8; j++)
          v[j] = (short)f2bf(Whh2[g2 * 64 + kc * 32 + q * 8 + j]);
        wreg[ty][kc] = v;
      }
    }
  }
  float bdr0 = 0.f, bdr1 = 0.f, bfr = 0.f;
  if (wv == 8) {
    bdr0 = bd[c];
    bdr1 = bd[16 + c];
    if (c < 2) bfr = bfv[c] + ob[c];
  }
  __syncthreads();

// ---- step macros (PAR/SLOT may be constants (hot) or runtime (decoder)) ----
#define L2_STEP(PAR)                                                          \
  do { if (isL2) {                                                            \
    const u16* Xc_ = X1[(PAR)];                                               \
    const u16* Hp_ = H2B[(PAR)];                                              \
    u16* Hd_ = H2B[(PAR) ^ 1];                                                \
    f32x4 a0 = (f32x4){br[0], br[0], br[0], br[0]};                           \
    f32x4 a1 = (f32x4){br[1], br[1], br[1], br[1]};                           \
    f32x4 a2 = (f32x4){br[2], br[2], br[2], br[2]};                           \
    f32x4 a3 = (f32x4){br[3], br[3], br[3], br[3]};                           \
    __builtin_amdgcn_s_setprio(1);                                            \
    _Pragma("unroll") for (int kc = 0; kc < 4; kc++) {                        \
      const short8 fh = *(const short8*)&Xc_[cX1 + kc * 32 + q8];             \
      a0 = mfma_(fh, *(const short8*)&W2F[(w2o + 0 + kc) * 512 + l8], a0);    \
      a1 = mfma_(fh, *(const short8*)&W2F[(w2o + 4 + kc) * 512 + l8], a1);    \
      a2 = mfma_(fh, *(const short8*)&W2F[(w2o + 8 + kc) * 512 + l8], a2);    \
      a3 = mfma_(fh, *(const short8*)&W2F[(w2o + 12 + kc) * 512 + l8], a3);   \
    }                                                                         \
    _Pragma("unroll") for (int kc = 0; kc < 2; kc++) {                        \
      const short8 hh = *(const short8*)&Hp_[cH2 + kc * 32 + q8];             \
      a0 = mfma_(hh, wreg[0][kc], a0);                                        \
      a1 = mfma_(hh, wreg[1][kc], a1);                                        \
      a2 = mfma_(hh, wreg[2][kc], a2);                                        \
      a3 = mfma_(hh, wreg[3][kc], a3);                                        \
    }                                                                         \
    __builtin_amdgcn_s_setprio(0);                                            \
    const float h0_ = cellr(a0[0], a1[0], a2[0], a3[0], cs0);                 \
    const float h1_ = cellr(a0[1], a1[1], a2[1], a3[1], cs1);                 \
    const float h2_ = cellr(a0[2], a1[2], a2[2], a3[2], cs2);                 \
    const float h3_ = cellr(a0[3], a1[3], a2[3], a3[3], cs3);                 \
    const u32 p01 = pkbf(h0_, h1_), p23 = pkbf(h2_, h3_);                     \
    Hd_[(q4 + 0) * H2S + u2b] = (u16)p01;                                     \
    Hd_[(q4 + 1) * H2S + u2b] = (u16)(p01 >> 16);                             \
    Hd_[(q4 + 2) * H2S + u2b] = (u16)p23;                                     \
    Hd_[(q4 + 3) * H2S + u2b] = (u16)(p23 >> 16);                             \
  } } while (0)

#define L1_STEP(PAR, SLOT, XRP)                                               \
  do { if (isL1) {                                                            \
    const u16* Xc_ = X1[(PAR)];                                               \
    u16* Xn_ = X1[(PAR) ^ 1];                                                 \
    f32x4 a0 = (f32x4){br[0], br[0], br[0], br[0]};                           \
    f32x4 a1 = (f32x4){br[1], br[1], br[1], br[1]};                           \
    f32x4 a2 = (f32x4){br[2], br[2], br[2], br[2]};                           \
    f32x4 a3 = (f32x4){br[3], br[3], br[3], br[3]};                           \
    __builtin_amdgcn_s_setprio(1);                                            \
    _Pragma("unroll") for (int kc = 0; kc < 4; kc++) {                        \
      const short8 ah = *(const short8*)&Xc_[cX1 + kc * 32 + q8];             \
      a0 = mfma_(ah, wreg[0][kc], a0);                                        \
      a1 = mfma_(ah, wreg[1][kc], a1);                                        \
      a2 = mfma_(ah, wreg[2][kc], a2);                                        \
      a3 = mfma_(ah, wreg[3][kc], a3);                                        \
    }                                                                         \
    {                                                                         \
      const short8 ax = *(const short8*)&(XRP)[cXC + (SLOT) * 40 + q8];       \
      a0 = mfma_(ax, *(const short8*)&W1xF[(0 * 8 + wv) * 512 + l8], a0);     \
      a1 = mfma_(ax, *(const short8*)&W1xF[(1 * 8 + wv) * 512 + l8], a1);     \
      a2 = mfma_(ax, *(const short8*)&W1xF[(2 * 8 + wv) * 512 + l8], a2);     \
      a3 = mfma_(ax, *(const short8*)&W1xF[(3 * 8 + wv) * 512 + l8], a3);     \
    }                                                                         \
    __builtin_amdgcn_s_setprio(0);                                            \
    const float h0_ = cellr(a0[0], a1[0], a2[0], a3[0], cs0);                 \
    const float h1_ = cellr(a0[1], a1[1], a2[1], a3[1], cs1);                 \
    const float h2_ = cellr(a0[2], a1[2], a2[2], a3[2], cs2);                 \
    const float h3_ = cellr(a0[3], a1[3], a2[3], a3[3], cs3);                 \
    const u32 p01 = pkbf(h0_, h1_), p23 = pkbf(h2_, h3_);                     \
    Xn_[(q4 + 0) * X1S + u2] = (u16)p01;                                      \
    Xn_[(q4 + 1) * X1S + u2] = (u16)(p01 >> 16);                              \
    Xn_[(q4 + 2) * X1S + u2] = (u16)p23;                                      \
    Xn_[(q4 + 3) * X1S + u2] = (u16)(p23 >> 16);                              \
  } } while (0)

  // ---- encoder: 25 chunks x 8 unrolled steps (t = 8m + j, parity = j&1) ----
  #pragma unroll 1
  for (int m = 0; m < 25; ++m) {
    const u16* xr = XCH[m & 1];
    u16* xw = XCH[(m & 1) ^ 1];

    // j = 0: issue next-chunk loads early (hide HBM under L2 MFMAs)
    float4v stg0, stg1;
    const bool doLd = isL2 && (m < 24);
    const int i0 = tid - 512;
    const int r0 = i0 >> 5, rem0 = i0 & 31, st0 = rem0 >> 2, hf0 = rem0 & 3;
    const int i1 = i0 + 256;
    const int r1 = i1 >> 5, rem1 = i1 & 31, st1 = rem1 >> 2, hf1 = rem1 & 3;
    if (doLd) {
      const int t0 = (m + 1) << 3;
      stg0 = *(const float4v*)&xh[(bb + r0) * 3200 + (t0 + st0) * 16 + hf0 * 4];
      stg1 = *(const float4v*)&xh[(bb + r1) * 3200 + (t0 + st1) * 16 + hf1 * 4];
    }
    if (m) L2_STEP(0);
    if (doLd) {
      *(uint2v*)&xw[r0 * XCS + st0 * 40 + hf0 * 4] =
          (uint2v){pkbf(stg0[0], stg0[1]), pkbf(stg0[2], stg0[3])};
      *(uint2v*)&xw[r1 * XCS + st1 * 40 + hf1 * 4] =
          (uint2v){pkbf(stg1[0], stg1[1]), pkbf(stg1[2], stg1[3])};
    } else if (isL2 && m == 24) {                     // decoder chunk 25 (xfr)
      const int t0 = 200;
      for (int e = i0; e < 16 * 8 * 14; e += 256) {
        const int r = e / 112, rem2 = e % 112, st = rem2 / 14, f = rem2 % 14;
        (void)t0;
        xw[r * XCS + st * 40 + f] = f2bf(xfr[(bb + r) * 280 + st * 14 + f]);
      }
      if (i0 < 32) {                                  // s=0 feats 14,15
        const int r = i0 >> 1, f = 14 + (i0 & 1);
        xw[r * XCS + f] = f2bf(xh[(bb + r) * 3200 + 199 * 16 + f]);
      }
    }
    L1_STEP(0, 0, xr);
    __syncthreads();

    L2_STEP(1); L1_STEP(1, 1, xr); __syncthreads();
    L2_STEP(0); L1_STEP(0, 2, xr); __syncthreads();
    L2_STEP(1); L1_STEP(1, 3, xr); __syncthreads();
    L2_STEP(0); L1_STEP(0, 4, xr); __syncthreads();
    L2_STEP(1); L1_STEP(1, 5, xr); __syncthreads();
    L2_STEP(0); L1_STEP(0, 6, xr); __syncthreads();
    L2_STEP(1); L1_STEP(1, 7, xr); __syncthreads();
  }

  // ---- t = 200 (first decoder input, no head yet) + load chunk 26 ----
  {
    L2_STEP(0);
    if (isL2) {                                       // chunk 26 -> XCH[0]
      u16* dst = (u16*)XCH[0];
      const int i0 = tid - 512;
      for (int e = i0; e < 16 * 8 * 14; e += 256) {
        const int r = e / 112, rem2 = e % 112, st = rem2 / 14, f = rem2 % 14;
        dst[r * XCS + st * 40 + f] = f2bf(xfr[(bb + r) * 280 + (8 + st) * 14 + f]);
      }
    }
    L1_STEP(0, 0, XCH[1]);
    __syncthreads();
  }

  // ---- decoder: t = 201..220 (cold path, rolled) ----
  #pragma unroll 1
  for (int t = 201; t <= 220; ++t) {
    L2_STEP(t & 1);
    if (isL2 && t == 208) {                           // chunk 27 -> XCH[1]
      u16* dst = (u16*)XCH[1];
      const int i0 = tid - 512;
      for (int e = i0; e < 16 * 8 * 14; e += 256) {
        const int r = e / 112, rem2 = e % 112, st = rem2 / 14, f = rem2 % 14;
        if (16 + st < 20)
          dst[r * XCS + st * 40 + f] = f2bf(xfr[(bb + r) * 280 + (16 + st) * 14 + f]);
      }
    }
    __syncthreads();                                  // #1: h2(t-1) visible
    if (wv == 8) {
      u16* Hd_ = H2B[(t & 1) ^ 1];
      f32x4 d0 = (f32x4){bdr0, bdr0, bdr0, bdr0};
      f32x4 d1 = (f32x4){bdr1, bdr1, bdr1, bdr1};
      #pragma unroll
      for (int kc = 0; kc < 2; kc++) {
        const short8 ad = *(const short8*)&Hd_[cH2 + kc * 32 + q8];
        d0 = mfma_(ad, *(const short8*)&WdF[(0 + kc) * 512 + l8], d0);
        d1 = mfma_(ad, *(const short8*)&WdF[(2 + kc) * 512 + l8], d1);
      }
      #pragma unroll
      for (int r = 0; r < 4; r++) {
        DB[(q4 + r) * DBS + c]      = f2bf(fmaxf(d0[r], 0.f));
        DB[(q4 + r) * DBS + 16 + c] = f2bf(fmaxf(d1[r], 0.f));
      }
      // same-wave write->read: compiler inserts lgkmcnt
      const short8 ap  = *(const short8*)&DB[c * DBS + q8];
      const short8 wfv = *(const short8*)&WfF[l8];
      f32x4 accp = (f32x4){bfr, bfr, bfr, bfr};
      accp = mfma_(ap, wfv, accp);
      if (c < 2) {
        u16* slot = &XCH[(t >> 3) & 1][0];
        #pragma unroll
        for (int r = 0; r < 4; r++) {
          const int b = q4 + r;
          out[(bb + b) * 40 + (t - 201) * 2 + c] = accp[r];
          slot[b * XCS + (t & 7) * 40 + 14 + c] = f2bf(accp[r]);  // pred -> x(t)
        }
      }
    }
    __syncthreads();                                  // #2: pred in XCH visible
    if (t <= 219) L1_STEP(t & 1, t & 7, XCH[(t >> 3) & 1]);
    __syncthreads();                                  // end of step
  }
}

extern "C" void kernel_launch(void* const* d_in, const int* in_sizes, int n_in,
                              void* d_out, int out_size, void* d_ws, size_t ws_size,
                              hipStream_t stream) {
  (void)in_sizes; (void)n_in; (void)out_size; (void)d_ws; (void)ws_size;
  spc_lstm<<<dim3(256), dim3(768), 0, stream>>>(
      (const float*)d_in[0],  (const float*)d_in[1],
      (const float*)d_in[2],  (const float*)d_in[3],
      (const float*)d_in[4],  (const float*)d_in[5],
      (const float*)d_in[6],  (const float*)d_in[7],
      (const float*)d_in[8],  (const float*)d_in[9],
      (const float*)d_in[10], (const float*)d_in[11],
      (const float*)d_in[12], (const float*)d_in[13],
      (const float*)d_in[14], (float*)d_out);
}